// Round 1
// baseline (442.261 us; speedup 1.0000x reference)
//
#include <hip/hip_runtime.h>

#define B_ROWS 32768
#define C_COLS 1000

__global__ __launch_bounds__(256) void bsl_hist(const int* __restrict__ target,
                                                float* __restrict__ freq, int n) {
    int i = blockIdx.x * blockDim.x + threadIdx.x;
    if (i < n) {
        atomicAdd(&freq[target[i]], 1.0f);
    }
}

__global__ __launch_bounds__(256) void bsl_main(const float* __restrict__ pred,
                                                const int* __restrict__ target,
                                                const float* __restrict__ freq,
                                                float* __restrict__ acc) {
    __shared__ float sfreq[C_COLS];
    __shared__ float swave[4];
    const int tid = threadIdx.x;

    // Stage the 1000-entry frequency table into LDS once per block.
    for (int i = tid; i < C_COLS; i += 256) sfreq[i] = freq[i];
    __syncthreads();

    for (int row = blockIdx.x; row < B_ROWS; row += gridDim.x) {
        const float4* prow = reinterpret_cast<const float4*>(pred + (size_t)row * C_COLS);
        float partial = 0.0f;
        // 1000 floats = 250 float4; threads 0..249 take one each.
        for (int j = tid; j < C_COLS / 4; j += 256) {
            float4 v = prow[j];
            const int fb = 4 * j;
            partial += __expf(v.x) * sfreq[fb + 0]
                     + __expf(v.y) * sfreq[fb + 1]
                     + __expf(v.z) * sfreq[fb + 2]
                     + __expf(v.w) * sfreq[fb + 3];
        }
        // wave64 butterfly reduce
        float v = partial;
        #pragma unroll
        for (int off = 32; off > 0; off >>= 1) v += __shfl_down(v, off, 64);
        if ((tid & 63) == 0) swave[tid >> 6] = v;
        __syncthreads();
        if (tid == 0) {
            float rowsum = swave[0] + swave[1] + swave[2] + swave[3];
            int t = target[row];
            float pt = pred[(size_t)row * C_COLS + t];
            // -picked = log_norm - pred_t - log(freq_t)
            atomicAdd(acc, logf(rowsum) - pt - logf(sfreq[t]));
        }
        __syncthreads();  // protect swave before next row
    }
}

__global__ void bsl_finalize(const float* __restrict__ acc, float* __restrict__ out) {
    out[0] = acc[0] / (float)B_ROWS;
}

extern "C" void kernel_launch(void* const* d_in, const int* in_sizes, int n_in,
                              void* d_out, int out_size, void* d_ws, size_t ws_size,
                              hipStream_t stream) {
    const float* pred = (const float*)d_in[0];
    const int* target = (const int*)d_in[1];

    float* freq = (float*)d_ws;        // [1000] histogram (padded to 1024)
    float* acc  = freq + 1024;         // [1] loss accumulator

    // Zero our scratch every call (harness does not re-poison between replays).
    hipMemsetAsync(d_ws, 0, 1025 * sizeof(float), stream);

    bsl_hist<<<(B_ROWS + 255) / 256, 256, 0, stream>>>(target, freq, B_ROWS);
    bsl_main<<<2048, 256, 0, stream>>>(pred, target, freq, acc);
    bsl_finalize<<<1, 1, 0, stream>>>(acc, (float*)d_out);
}

// Round 2
// 36.749 us; speedup vs baseline: 12.0348x; 12.0348x over previous
//
#include <hip/hip_runtime.h>

#define B_ROWS 32768
#define C_COLS 1000
#define NF4 250           // C_COLS / 4
#define MAIN_BLOCKS 2048
#define WAVES_TOTAL (MAIN_BLOCKS * 4)

// --- histogram: LDS per-block counts, then sparse global fp32 adds ---
__global__ __launch_bounds__(256) void bsl_hist(const int* __restrict__ target,
                                                float* __restrict__ freq) {
    __shared__ unsigned int lh[C_COLS];
    const int tid = threadIdx.x;
    for (int i = tid; i < C_COLS; i += 256) lh[i] = 0u;
    __syncthreads();
    // 16 blocks x 2048 labels; 8 labels/thread via int4
    const int4* t4 = reinterpret_cast<const int4*>(target + blockIdx.x * 2048);
    #pragma unroll
    for (int k = 0; k < 2; ++k) {
        int4 v = t4[tid + k * 256];
        atomicAdd(&lh[v.x], 1u);
        atomicAdd(&lh[v.y], 1u);
        atomicAdd(&lh[v.z], 1u);
        atomicAdd(&lh[v.w], 1u);
    }
    __syncthreads();
    for (int i = tid; i < C_COLS; i += 256) {
        unsigned int c = lh[i];
        if (c) atomicAdd(&freq[i], (float)c);
    }
}

// --- main: one wave per row, no barriers in the row loop, no atomics ---
__global__ __launch_bounds__(256) void bsl_main(const float* __restrict__ pred,
                                                const int* __restrict__ target,
                                                const float* __restrict__ freq,
                                                float* __restrict__ partials) {
    __shared__ float sfreq[C_COLS];
    __shared__ float swave[4];
    const int tid = threadIdx.x;
    const int lane = tid & 63;
    const int wib = tid >> 6;

    for (int i = tid; i < C_COLS; i += 256) sfreq[i] = freq[i];
    __syncthreads();
    const float4* sf4 = reinterpret_cast<const float4*>(sfreq);

    const int gwid = blockIdx.x * 4 + wib;
    float local = 0.0f;

    for (int row = gwid; row < B_ROWS; row += WAVES_TOTAL) {
        const int t = target[row];
        const float4* prow = reinterpret_cast<const float4*>(pred + (size_t)row * C_COLS);
        const int t4i = t >> 2, tm = t & 3;
        float partial = 0.0f, pt = 0.0f;
        #pragma unroll
        for (int k = 0; k < 4; ++k) {
            const int j = k * 64 + lane;          // k<3 always in range (j<=191)
            if (j < NF4) {
                const float4 v = prow[j];
                const float4 f = sf4[j];
                partial += __expf(v.x) * f.x + __expf(v.y) * f.y
                         + __expf(v.z) * f.z + __expf(v.w) * f.w;
                if (j == t4i)
                    pt = (tm & 1) ? ((tm & 2) ? v.w : v.y)
                                  : ((tm & 2) ? v.z : v.x);
            }
        }
        // wave64 butterfly: every lane ends with the full row sum
        #pragma unroll
        for (int off = 32; off > 0; off >>= 1)
            partial += __shfl_xor(partial, off, 64);
        // broadcast target logit from the lane that loaded it
        const float ptb = __shfl(pt, t4i & 63, 64);
        local += logf(partial) - ptb - logf(sfreq[t]);
    }

    // `local` is identical across the wave; block-reduce 4 wave values
    if (lane == 0) swave[wib] = local;
    __syncthreads();
    if (tid == 0)
        partials[blockIdx.x] = swave[0] + swave[1] + swave[2] + swave[3];
}

__global__ __launch_bounds__(256) void bsl_finalize(const float* __restrict__ partials,
                                                    float* __restrict__ out) {
    const int tid = threadIdx.x;
    float s = 0.0f;
    for (int i = tid; i < MAIN_BLOCKS; i += 256) s += partials[i];
    #pragma unroll
    for (int off = 32; off > 0; off >>= 1) s += __shfl_xor(s, off, 64);
    __shared__ float sw[4];
    if ((tid & 63) == 0) sw[tid >> 6] = s;
    __syncthreads();
    if (tid == 0) out[0] = (sw[0] + sw[1] + sw[2] + sw[3]) / (float)B_ROWS;
}

extern "C" void kernel_launch(void* const* d_in, const int* in_sizes, int n_in,
                              void* d_out, int out_size, void* d_ws, size_t ws_size,
                              hipStream_t stream) {
    const float* pred = (const float*)d_in[0];
    const int* target = (const int*)d_in[1];

    float* freq     = (float*)d_ws;          // [1024] histogram
    float* partials = freq + 1024;           // [MAIN_BLOCKS]

    // freq must start at zero every call (hist accumulates into it)
    hipMemsetAsync(freq, 0, 1024 * sizeof(float), stream);

    bsl_hist<<<16, 256, 0, stream>>>(target, freq);
    bsl_main<<<MAIN_BLOCKS, 256, 0, stream>>>(pred, target, freq, partials);
    bsl_finalize<<<1, 256, 0, stream>>>(partials, (float*)d_out);
}